// Round 5
// baseline (149.233 us; speedup 1.0000x reference)
//
#include <hip/hip_runtime.h>

typedef unsigned short u16;
typedef __attribute__((ext_vector_type(8))) short short8;
typedef __attribute__((ext_vector_type(4))) float f32x4;

#define N_NODES 50000
#define C_ 128
#define E_ 10
#define NT_ 16
#define GRID_MAIN 512
#define K0_ 640
#define K1_ 512

// fragment-linear weight buffers:
// WF0: [E][8 waves][20 slots][64 lanes][8 elems] bf16
// WF1: [E][8 waves][16 slots][64 lanes][8 elems] bf16
#define WF0_BYTES (E_ * 8 * 20 * 512 * 2)        // 1,638,400
#define WF1_BYTES (E_ * 8 * 16 * 512 * 2)        // 1,310,720
#define CNT_OFF   (WF0_BYTES + WF1_BYTES)
#define LIST_OFF  (CNT_OFF + 64)

__device__ __forceinline__ u16 f2bf(float f){ union{unsigned u; float f;} v; v.f = f; unsigned u = v.u; u += 0x7FFFu + ((u>>16)&1u); return (u16)(u>>16); }

// MFMA-based weight prep (validated r4): grid = E_*9 blocks of 256 threads.
__global__ __launch_bounds__(256) void prep_weights_kernel(
    const float* __restrict__ tp2, const float* __restrict__ tp3,
    const float* __restrict__ c00, const float* __restrict__ c10, const float* __restrict__ c20,
    const float* __restrict__ c01, const float* __restrict__ c11, const float* __restrict__ c21,
    const float* __restrict__ lin0, const float* __restrict__ lin1,
    u16* __restrict__ WF0, u16* __restrict__ WF1)
{
    const int b = blockIdx.x;
    const int e = b / 9, kb = b % 9;
    const int which = (kb >= 5) ? 1 : 0;
    const int seg = which ? kb - 5 : kb;
    const float* __restrict__ lin = which ? lin1 : lin0;

    __shared__ u16 R[128 * 136];
    __shared__ u16 LT[128 * 132];

    const int tid = threadIdx.x;
    const float NC = 0.08838834764831845f;

    for (int t = tid; t < 128 * 32; t += 256) {
        const int jj = t >> 5, c4 = (t & 31) << 2;
        const float4 v = *(const float4*)(lin + jj * 128 + c4);
        LT[(c4 + 0) * 132 + jj] = f2bf(v.x * NC);
        LT[(c4 + 1) * 132 + jj] = f2bf(v.y * NC);
        LT[(c4 + 2) * 132 + jj] = f2bf(v.z * NC);
        LT[(c4 + 3) * 132 + jj] = f2bf(v.w * NC);
    }

    {
        const int c = tid >> 1, jh = (tid & 1) * 64;
        const float i128 = 0.08838834764831845f;
        const float i256 = 0.0625f;
        const float i512 = 0.04419417382415922f;
        const float I3   = 0.5773502691896258f;
        const float I9   = I3 * I3;
        const float t2_0 = tp2[0*C_+c], t2_1 = tp2[1*C_+c], t2_2 = tp2[2*C_+c], t2_3 = tp2[3*C_+c];
        const float t3_0 = tp3[0*C_+c], t3_1 = tp3[1*C_+c], t3_2 = tp3[2*C_+c];
        const float t3_3 = tp3[3*C_+c], t3_4 = tp3[4*C_+c], t3_5 = tp3[5*C_+c];
        const float t3_6 = tp3[6*C_+c], t3_7 = tp3[7*C_+c];

        const float* P0; const float* P1 = nullptr; const float* P2 = nullptr;
        float a0 = 0.f, a1 = 0.f, a2 = 0.f;
        if (!which) {
            const float* C0 = c00 + (size_t)e * C_   * C_;
            const float* C1 = c10 + (size_t)e * 2*C_ * C_;
            const float* C2 = c20 + (size_t)e * 4*C_ * C_;
            switch (seg) {
            case 0: P0 = C0 + c*C_;          a0 = i128; break;
            case 1: P0 = C1 + c*C_;          a0 = t2_0 * i256; break;
            case 2: P0 = C1 + (C_+c)*C_;     a0 = t2_3 * I3 * i256; break;
            case 3: P0 = C2 + c*C_;          a0 = t3_0 * t2_0 * i512; break;
            default:
                P0 = C2 + (C_+c)*C_;         a0 = t3_3 * t2_1 * I9 * i512;
                P1 = C2 + (2*C_+c)*C_;       a1 = t3_5 * t2_2 * I9 * i512;
                P2 = C2 + (3*C_+c)*C_;       a2 = t3_6 * t2_3 * I3 * i512; break;
            }
        } else {
            const float* C0 = c01 + (size_t)e * C_   * C_;
            const float* C1 = c11 + (size_t)e * 2*C_ * C_;
            const float* C2 = c21 + (size_t)e * 4*C_ * C_;
            switch (seg) {
            case 0: P0 = C0 + c*C_;          a0 = i128; break;
            case 1: P0 = C1 + c*C_;          a0 = t2_1 * I3 * i256;
                    P1 = C1 + (C_+c)*C_;     a1 = t2_2 * I3 * i256; break;
            case 2: P0 = C2 + c*C_;          a0 = t3_1 * t2_0 * I3 * i512;
                    P1 = C2 + (C_+c)*C_;     a1 = t3_2 * t2_1 * I9 * i512;
                    P2 = C2 + (2*C_+c)*C_;   a2 = t3_4 * t2_2 * I9 * i512; break;
            default: P0 = C2 + (3*C_+c)*C_;  a0 = t3_7 * t2_3 * I9 * i512; break;
            }
        }
        for (int j4 = 0; j4 < 64; j4 += 4) {
            const int jj = jh + j4;
            const float4 v = *(const float4*)(P0 + jj);
            float r0 = a0*v.x, r1 = a0*v.y, r2 = a0*v.z, r3 = a0*v.w;
            if (P1) {
                const float4 u = *(const float4*)(P1 + jj);
                r0 += a1*u.x; r1 += a1*u.y; r2 += a1*u.z; r3 += a1*u.w;
            }
            if (P2) {
                const float4 u = *(const float4*)(P2 + jj);
                r0 += a2*u.x; r1 += a2*u.y; r2 += a2*u.z; r3 += a2*u.w;
            }
            ushort4 st; st.x = f2bf(r0); st.y = f2bf(r1); st.z = f2bf(r2); st.w = f2bf(r3);
            *(ushort4*)&R[c * 136 + jj] = st;
        }
    }
    __syncthreads();

    const int wv = tid >> 6, l = tid & 63;
    const int lcol = l & 15, gD = l >> 4;
    f32x4 acc[2][8];
#pragma unroll
    for (int s = 0; s < 2; ++s)
#pragma unroll
        for (int t = 0; t < 8; ++t) acc[s][t] = (f32x4){0.f, 0.f, 0.f, 0.f};

#pragma unroll
    for (int ks2 = 0; ks2 < 4; ++ks2) {
        const int jj0 = ks2 * 32 + gD * 4;
        short8 bf[8];
#pragma unroll
        for (int t = 0; t < 8; ++t) {
            const int colB = t * 16 + lcol;
            union { unsigned long long q[2]; short8 v; } u;
            u.q[0] = *(const unsigned long long*)&LT[colB * 132 + jj0];
            u.q[1] = *(const unsigned long long*)&LT[colB * 132 + jj0 + 16];
            bf[t] = u.v;
        }
#pragma unroll
        for (int s = 0; s < 2; ++s) {
            const int krow = (wv + s * 4) * 16 + lcol;
            union { unsigned long long q[2]; short8 v; } ua;
            ua.q[0] = *(const unsigned long long*)&R[krow * 136 + jj0];
            ua.q[1] = *(const unsigned long long*)&R[krow * 136 + jj0 + 16];
#pragma unroll
            for (int t = 0; t < 8; ++t)
                acc[s][t] = __builtin_amdgcn_mfma_f32_16x16x32_bf16(ua.v, bf[t], acc[s][t], 0, 0, 0);
        }
    }

#pragma unroll
    for (int s = 0; s < 2; ++s) {
#pragma unroll
        for (int r = 0; r < 4; ++r) {
            const int k = (wv + s * 4) * 16 + 4 * gD + r;
            const int ks = k >> 5, r2 = k & 31;
            const int eh = r2 >> 4, g2 = (r2 >> 2) & 3, el = r2 & 3;
            const int elem = eh * 4 + el;
            const int lanef = lcol + 16 * g2;
            const int slot = seg * 4 + ks;
#pragma unroll
            for (int t = 0; t < 8; ++t) {
                const u16 wvl = f2bf(acc[s][t][r]);
                if (!which) WF0[(((size_t)(e*8 + t))*20 + slot)*512 + lanef*8 + elem] = wvl;
                else        WF1[(((size_t)(e*8 + t))*16 + slot)*512 + lanef*8 + elem] = wvl;
            }
        }
    }
}

__global__ void bucket_kernel(const float* __restrict__ attrs,
                              int* __restrict__ cnt, int* __restrict__ lists)
{
    __shared__ int lcnt[E_];
    __shared__ int lbase[E_];
    const int n = blockIdx.x * 256 + threadIdx.x;
    if (threadIdx.x < E_) lcnt[threadIdx.x] = 0;
    __syncthreads();
    int e = 0, my = 0;
    if (n < N_NODES) {
        const float* a = attrs + (size_t)n * E_;
#pragma unroll
        for (int i = 0; i < E_; ++i) if (a[i] > 0.5f) e = i;
        my = atomicAdd(&lcnt[e], 1);
    }
    __syncthreads();
    if (threadIdx.x < E_) lbase[threadIdx.x] = atomicAdd(&cnt[threadIdx.x], lcnt[threadIdx.x]);
    __syncthreads();
    if (n < N_NODES) lists[e*N_NODES + lbase[e] + my] = n;
}

// Persistent main: grid = 512 (2 blocks/CU), each block loops over tiles
// t = bx, bx+512, ... Cross-tile pipeline: during tile t's MFMA phase we
// issue tile t's sc loads (ks==1) and tile t+1's feats loads (ks==2).
__global__ __launch_bounds__(512, 4) void main_kernel(
    const float* __restrict__ feats, const float* __restrict__ sc,
    const int* __restrict__ cnt, const int* __restrict__ lists,
    const u16* __restrict__ WF0, const u16* __restrict__ WF1,
    float* __restrict__ out)
{
    __shared__ __align__(16) u16 Afull[68 * 512];   // 69,632 B (reused as out-stage)

    const int tid = threadIdx.x;
    const int bx = blockIdx.x;

    // cnt snapshot + tile starts in registers (unrolled, static indexing)
    int cr0 = cnt[0], cr1 = cnt[1], cr2 = cnt[2], cr3 = cnt[3], cr4 = cnt[4];
    int cr5 = cnt[5], cr6 = cnt[6], cr7 = cnt[7], cr8 = cnt[8], cr9 = cnt[9];
#define TC(x) (((x) + NT_ - 1) >> 4)
    const int t0 = 0;
    const int t1 = t0 + TC(cr0); const int t2 = t1 + TC(cr1);
    const int t3 = t2 + TC(cr2); const int t4 = t3 + TC(cr3);
    const int t5 = t4 + TC(cr4); const int t6 = t5 + TC(cr5);
    const int t7 = t6 + TC(cr6); const int t8 = t7 + TC(cr7);
    const int t9 = t8 + TC(cr8); const int ntiles = t9 + TC(cr9);
#undef TC

    const int node = tid >> 5;          // 0..15 (phase-1 & epilogue role)
    const int ch   = tid & 31;
    const int w = tid >> 6, l = tid & 63;
    const int lcol = l & 15, g = l >> 4;
    const int col = w*16 + lcol;

    if (bx >= ntiles) return;

    // map tile index -> (e, tile-in-e, this thread's node id)
    auto map_tile = [&](int t, int& e_, int& nn_) {
        int e = 9, base = t9, c = cr9;
        if (t < t1) { e = 0; base = t0; c = cr0; }
        else if (t < t2) { e = 1; base = t1; c = cr1; }
        else if (t < t3) { e = 2; base = t2; c = cr2; }
        else if (t < t4) { e = 3; base = t3; c = cr3; }
        else if (t < t5) { e = 4; base = t4; c = cr4; }
        else if (t < t6) { e = 5; base = t5; c = cr5; }
        else if (t < t7) { e = 6; base = t6; c = cr6; }
        else if (t < t8) { e = 7; base = t7; c = cr7; }
        else if (t < t9) { e = 8; base = t8; c = cr8; }
        const int tile = t - base;
        const int nv = min(NT_, c - tile * NT_);
        e_ = e;
        nn_ = (node < nv) ? lists[e*N_NODES + tile*NT_ + node] : -1;
    };

    int e, n;
    map_tile(bx, e, n);
    float4 f0 = make_float4(0,0,0,0), f1 = f0, f2 = f0, f3 = f0;
    if (n >= 0) {
        const float* f = feats + (size_t)n * 512;
        f0 = *(const float4*)(f + ch*4);
        f1 = *(const float4*)(f + 128 + ch*12);
        f2 = *(const float4*)(f + 128 + ch*12 + 4);
        f3 = *(const float4*)(f + 128 + ch*12 + 8);
    }

    for (int t = bx; t < ntiles; t += GRID_MAIN) {
        // ---------- phase 1: panels from prefetched regs -> LDS A ----------
        {
            float Sa[4]  = {f0.x, f0.y, f0.z, f0.w};
            float Va[12] = {f1.x,f1.y,f1.z,f1.w, f2.x,f2.y,f2.z,f2.w, f3.x,f3.y,f3.z,f3.w};

            u16 fsS[5][4];
            u16 fsV[4][3][4];
#pragma unroll
            for (int i = 0; i < 4; ++i) {
                const float S  = Sa[i];
                const float V0 = Va[3*i], V1 = Va[3*i+1], V2 = Va[3*i+2];
                const float S2 = S * S;
                const float VV = V0*V0 + V1*V1 + V2*V2;
                fsS[0][i] = f2bf(S);
                fsS[1][i] = f2bf(S2);
                fsS[2][i] = f2bf(VV);
                fsS[3][i] = f2bf(S2 * S);
                fsS[4][i] = f2bf(S * VV);
                const float Vm[3] = {V0, V1, V2};
#pragma unroll
                for (int m = 0; m < 3; ++m) {
                    fsV[0][m][i] = f2bf(Vm[m]);
                    fsV[1][m][i] = f2bf(S  * Vm[m]);
                    fsV[2][m][i] = f2bf(S2 * Vm[m]);
                    fsV[3][m][i] = f2bf(VV * Vm[m]);
                }
            }
            const int lane  = node + 16 * (ch & 3);
            const int ks    = ch >> 3;
            const int ebase = ((ch >> 2) & 1) * 4;
            const int lanep = lane ^ (ks << 1);
            u16* bp = &Afull[lanep*8 + ebase];
#pragma unroll
            for (int p = 0; p < 5; ++p)
                *(ushort4*)&bp[(p*4 + ks) * 512] = *(ushort4*)fsS[p];
#pragma unroll
            for (int q = 0; q < 4; ++q)
#pragma unroll
                for (int m = 0; m < 3; ++m)
                    *(ushort4*)&bp[(20 + q*12 + m*4 + ks) * 512] = *(ushort4*)fsV[q][m];
        }
        __syncthreads();

        // ---------- phase 2: MFMA + in-flight prefetches ----------
        const u16* WB0 = WF0 + ((size_t)(e*8 + w)) * (20*512) + l*8;
        const u16* WB1 = WF1 + ((size_t)(e*8 + w)) * (16*512) + l*8;

        f32x4 accS = {0.f, 0.f, 0.f, 0.f};
        f32x4 accV0 = accS, accV1 = accS, accV2 = accS;
        float4 scR0, scR1, scR2, scR3;
        int ne = e, nn = -1;

#pragma unroll
        for (int ks = 0; ks < 4; ++ks) {
            short8 bS[5], bV[4];
#pragma unroll
            for (int p = 0; p < 5; ++p) bS[p] = *(const short8*)(WB0 + (p*4 + ks) * 512);
#pragma unroll
            for (int q = 0; q < 4; ++q) bV[q] = *(const short8*)(WB1 + (q*4 + ks) * 512);

            if (ks == 1 && n >= 0) {               // sc for THIS tile's epilogue
                const float* sp = sc + (size_t)n * 512 + ch * 4;
                scR0 = *(const float4*)(sp);
                scR1 = *(const float4*)(sp + 128);
                scR2 = *(const float4*)(sp + 256);
                scR3 = *(const float4*)(sp + 384);
            }
            if (ks == 2) {                          // feats for NEXT tile
                const int tn = t + GRID_MAIN;
                f0 = make_float4(0,0,0,0); f1 = f0; f2 = f0; f3 = f0;
                if (tn < ntiles) {
                    map_tile(tn, ne, nn);
                    if (nn >= 0) {
                        const float* f = feats + (size_t)nn * 512;
                        f0 = *(const float4*)(f + ch*4);
                        f1 = *(const float4*)(f + 128 + ch*12);
                        f2 = *(const float4*)(f + 128 + ch*12 + 4);
                        f3 = *(const float4*)(f + 128 + ch*12 + 8);
                    }
                }
            }

            const int lp8 = (l ^ (ks << 1)) * 8;
#pragma unroll
            for (int p = 0; p < 5; ++p) {
                const short8 a = *(const short8*)&Afull[(p*4 + ks)*512 + lp8];
                accS = __builtin_amdgcn_mfma_f32_16x16x32_bf16(a, bS[p], accS, 0, 0, 0);
            }
#pragma unroll
            for (int q = 0; q < 4; ++q) {
                const short8 a0 = *(const short8*)&Afull[(20 + q*12 + 0*4 + ks)*512 + lp8];
                accV0 = __builtin_amdgcn_mfma_f32_16x16x32_bf16(a0, bV[q], accV0, 0, 0, 0);
                const short8 a1 = *(const short8*)&Afull[(20 + q*12 + 1*4 + ks)*512 + lp8];
                accV1 = __builtin_amdgcn_mfma_f32_16x16x32_bf16(a1, bV[q], accV1, 0, 0, 0);
                const short8 a2 = *(const short8*)&Afull[(20 + q*12 + 2*4 + ks)*512 + lp8];
                accV2 = __builtin_amdgcn_mfma_f32_16x16x32_bf16(a2, bV[q], accV2, 0, 0, 0);
            }
        }

        // ---------- phase 3: stage in LDS, coalesced epilogue ----------
        __syncthreads();                   // all A-reads done
        float* OutB = (float*)Afull;       // 16 x 516 floats
#pragma unroll
        for (int r = 0; r < 4; ++r) {
            const int nd = 4*g + r;
            OutB[nd*516 + col] = accS[r];
            OutB[nd*516 + 128 + 3*col + 0] = accV0[r];
            OutB[nd*516 + 128 + 3*col + 1] = accV1[r];
            OutB[nd*516 + 128 + 3*col + 2] = accV2[r];
        }
        __syncthreads();

        if (n >= 0) {
            const size_t gb = (size_t)n * 512 + ch * 4;
            const float4 v0 = *(const float4*)&OutB[node*516 + ch*4];
            const float4 v1 = *(const float4*)&OutB[node*516 + ch*4 + 128];
            const float4 v2 = *(const float4*)&OutB[node*516 + ch*4 + 256];
            const float4 v3 = *(const float4*)&OutB[node*516 + ch*4 + 384];
            float4 o0, o1, o2, o3;
            o0.x=v0.x+scR0.x; o0.y=v0.y+scR0.y; o0.z=v0.z+scR0.z; o0.w=v0.w+scR0.w;
            o1.x=v1.x+scR1.x; o1.y=v1.y+scR1.y; o1.z=v1.z+scR1.z; o1.w=v1.w+scR1.w;
            o2.x=v2.x+scR2.x; o2.y=v2.y+scR2.y; o2.z=v2.z+scR2.z; o2.w=v2.w+scR2.w;
            o3.x=v3.x+scR3.x; o3.y=v3.y+scR3.y; o3.z=v3.z+scR3.z; o3.w=v3.w+scR3.w;
            *(float4*)(out + gb)       = o0;
            *(float4*)(out + gb + 128) = o1;
            *(float4*)(out + gb + 256) = o2;
            *(float4*)(out + gb + 384) = o3;
        }
        __syncthreads();                   // OutB reads done before next A-writes

        e = ne; n = nn;
    }
}

extern "C" void kernel_launch(void* const* d_in, const int* in_sizes, int n_in,
                              void* d_out, int out_size, void* d_ws, size_t ws_size,
                              hipStream_t stream) {
    const float* feats = (const float*)d_in[0];
    const float* attrs = (const float*)d_in[1];
    const float* sc    = (const float*)d_in[2];
    const float* tp2   = (const float*)d_in[3];
    const float* tp3   = (const float*)d_in[4];
    const float* c00   = (const float*)d_in[5];
    const float* c01   = (const float*)d_in[6];
    const float* c10   = (const float*)d_in[7];
    const float* c11   = (const float*)d_in[8];
    const float* c20   = (const float*)d_in[9];
    const float* c21   = (const float*)d_in[10];
    const float* lin0  = (const float*)d_in[11];
    const float* lin1  = (const float*)d_in[12];
    float* out = (float*)d_out;

    char* ws = (char*)d_ws;
    u16* WF0   = (u16*)(ws);
    u16* WF1   = (u16*)(ws + WF0_BYTES);
    int* cnt   = (int*)(ws + CNT_OFF);
    int* lists = (int*)(ws + LIST_OFF);

    hipMemsetAsync(cnt, 0, 64, stream);
    hipLaunchKernelGGL(prep_weights_kernel, dim3(E_*9), dim3(256), 0, stream,
                       tp2, tp3, c00, c10, c20, c01, c11, c21, lin0, lin1, WF0, WF1);
    hipLaunchKernelGGL(bucket_kernel, dim3((N_NODES + 255)/256), dim3(256), 0, stream,
                       attrs, cnt, lists);
    hipLaunchKernelGGL(main_kernel, dim3(GRID_MAIN), dim3(512), 0, stream,
                       feats, sc, cnt, lists, WF0, WF1, out);
}

// Round 6
// 117.314 us; speedup vs baseline: 1.2721x; 1.2721x over previous
//
#include <hip/hip_runtime.h>

typedef unsigned short u16;
typedef __attribute__((ext_vector_type(8))) short short8;
typedef __attribute__((ext_vector_type(4))) float f32x4;

#define N_NODES 50000
#define C_ 128
#define E_ 10
#define NT_ 16
#define NBLK_MAIN 3200
#define K0_ 640
#define K1_ 512

// fragment-linear weight buffers:
// WF0: [E][8 waves][20 slots][64 lanes][8 elems] bf16  (slot = p*4+ks)
// WF1: [E][8 waves][16 slots][64 lanes][8 elems] bf16  (slot = q*4+ks)
#define WF0_BYTES (E_ * 8 * 20 * 512 * 2)        // 1,638,400
#define WF1_BYTES (E_ * 8 * 16 * 512 * 2)        // 1,310,720
#define CNT_OFF   (WF0_BYTES + WF1_BYTES)
#define LIST_OFF  (CNT_OFF + 64)

__device__ __forceinline__ u16 f2bf(float f){ union{unsigned u; float f;} v; v.f = f; unsigned u = v.u; u += 0x7FFFu + ((u>>16)&1u); return (u16)(u>>16); }

// MFMA-based weight prep (validated r4/r5): grid = E_*9 blocks of 256 threads.
__global__ __launch_bounds__(256) void prep_weights_kernel(
    const float* __restrict__ tp2, const float* __restrict__ tp3,
    const float* __restrict__ c00, const float* __restrict__ c10, const float* __restrict__ c20,
    const float* __restrict__ c01, const float* __restrict__ c11, const float* __restrict__ c21,
    const float* __restrict__ lin0, const float* __restrict__ lin1,
    u16* __restrict__ WF0, u16* __restrict__ WF1)
{
    const int b = blockIdx.x;
    const int e = b / 9, kb = b % 9;
    const int which = (kb >= 5) ? 1 : 0;
    const int seg = which ? kb - 5 : kb;
    const float* __restrict__ lin = which ? lin1 : lin0;

    __shared__ u16 R[128 * 136];
    __shared__ u16 LT[128 * 132];

    const int tid = threadIdx.x;
    const float NC = 0.08838834764831845f;

    for (int t = tid; t < 128 * 32; t += 256) {
        const int jj = t >> 5, c4 = (t & 31) << 2;
        const float4 v = *(const float4*)(lin + jj * 128 + c4);
        LT[(c4 + 0) * 132 + jj] = f2bf(v.x * NC);
        LT[(c4 + 1) * 132 + jj] = f2bf(v.y * NC);
        LT[(c4 + 2) * 132 + jj] = f2bf(v.z * NC);
        LT[(c4 + 3) * 132 + jj] = f2bf(v.w * NC);
    }

    {
        const int c = tid >> 1, jh = (tid & 1) * 64;
        const float i128 = 0.08838834764831845f;
        const float i256 = 0.0625f;
        const float i512 = 0.04419417382415922f;
        const float I3   = 0.5773502691896258f;
        const float I9   = I3 * I3;
        const float t2_0 = tp2[0*C_+c], t2_1 = tp2[1*C_+c], t2_2 = tp2[2*C_+c], t2_3 = tp2[3*C_+c];
        const float t3_0 = tp3[0*C_+c], t3_1 = tp3[1*C_+c], t3_2 = tp3[2*C_+c];
        const float t3_3 = tp3[3*C_+c], t3_4 = tp3[4*C_+c], t3_5 = tp3[5*C_+c];
        const float t3_6 = tp3[6*C_+c], t3_7 = tp3[7*C_+c];

        const float* P0; const float* P1 = nullptr; const float* P2 = nullptr;
        float a0 = 0.f, a1 = 0.f, a2 = 0.f;
        if (!which) {
            const float* C0 = c00 + (size_t)e * C_   * C_;
            const float* C1 = c10 + (size_t)e * 2*C_ * C_;
            const float* C2 = c20 + (size_t)e * 4*C_ * C_;
            switch (seg) {
            case 0: P0 = C0 + c*C_;          a0 = i128; break;
            case 1: P0 = C1 + c*C_;          a0 = t2_0 * i256; break;
            case 2: P0 = C1 + (C_+c)*C_;     a0 = t2_3 * I3 * i256; break;
            case 3: P0 = C2 + c*C_;          a0 = t3_0 * t2_0 * i512; break;
            default:
                P0 = C2 + (C_+c)*C_;         a0 = t3_3 * t2_1 * I9 * i512;
                P1 = C2 + (2*C_+c)*C_;       a1 = t3_5 * t2_2 * I9 * i512;
                P2 = C2 + (3*C_+c)*C_;       a2 = t3_6 * t2_3 * I3 * i512; break;
            }
        } else {
            const float* C0 = c01 + (size_t)e * C_   * C_;
            const float* C1 = c11 + (size_t)e * 2*C_ * C_;
            const float* C2 = c21 + (size_t)e * 4*C_ * C_;
            switch (seg) {
            case 0: P0 = C0 + c*C_;          a0 = i128; break;
            case 1: P0 = C1 + c*C_;          a0 = t2_1 * I3 * i256;
                    P1 = C1 + (C_+c)*C_;     a1 = t2_2 * I3 * i256; break;
            case 2: P0 = C2 + c*C_;          a0 = t3_1 * t2_0 * I3 * i512;
                    P1 = C2 + (C_+c)*C_;     a1 = t3_2 * t2_1 * I9 * i512;
                    P2 = C2 + (2*C_+c)*C_;   a2 = t3_4 * t2_2 * I9 * i512; break;
            default: P0 = C2 + (3*C_+c)*C_;  a0 = t3_7 * t2_3 * I9 * i512; break;
            }
        }
        for (int j4 = 0; j4 < 64; j4 += 4) {
            const int jj = jh + j4;
            const float4 v = *(const float4*)(P0 + jj);
            float r0 = a0*v.x, r1 = a0*v.y, r2 = a0*v.z, r3 = a0*v.w;
            if (P1) {
                const float4 u = *(const float4*)(P1 + jj);
                r0 += a1*u.x; r1 += a1*u.y; r2 += a1*u.z; r3 += a1*u.w;
            }
            if (P2) {
                const float4 u = *(const float4*)(P2 + jj);
                r0 += a2*u.x; r1 += a2*u.y; r2 += a2*u.z; r3 += a2*u.w;
            }
            ushort4 st; st.x = f2bf(r0); st.y = f2bf(r1); st.z = f2bf(r2); st.w = f2bf(r3);
            *(ushort4*)&R[c * 136 + jj] = st;
        }
    }
    __syncthreads();

    const int wv = tid >> 6, l = tid & 63;
    const int lcol = l & 15, gD = l >> 4;
    f32x4 acc[2][8];
#pragma unroll
    for (int s = 0; s < 2; ++s)
#pragma unroll
        for (int t = 0; t < 8; ++t) acc[s][t] = (f32x4){0.f, 0.f, 0.f, 0.f};

#pragma unroll
    for (int ks2 = 0; ks2 < 4; ++ks2) {
        const int jj0 = ks2 * 32 + gD * 4;
        short8 bf[8];
#pragma unroll
        for (int t = 0; t < 8; ++t) {
            const int colB = t * 16 + lcol;
            union { unsigned long long q[2]; short8 v; } u;
            u.q[0] = *(const unsigned long long*)&LT[colB * 132 + jj0];
            u.q[1] = *(const unsigned long long*)&LT[colB * 132 + jj0 + 16];
            bf[t] = u.v;
        }
#pragma unroll
        for (int s = 0; s < 2; ++s) {
            const int krow = (wv + s * 4) * 16 + lcol;
            union { unsigned long long q[2]; short8 v; } ua;
            ua.q[0] = *(const unsigned long long*)&R[krow * 136 + jj0];
            ua.q[1] = *(const unsigned long long*)&R[krow * 136 + jj0 + 16];
#pragma unroll
            for (int t = 0; t < 8; ++t)
                acc[s][t] = __builtin_amdgcn_mfma_f32_16x16x32_bf16(ua.v, bf[t], acc[s][t], 0, 0, 0);
        }
    }

#pragma unroll
    for (int s = 0; s < 2; ++s) {
#pragma unroll
        for (int r = 0; r < 4; ++r) {
            const int k = (wv + s * 4) * 16 + 4 * gD + r;
            const int ks = k >> 5, r2 = k & 31;
            const int eh = r2 >> 4, g2 = (r2 >> 2) & 3, el = r2 & 3;
            const int elem = eh * 4 + el;
            const int lanef = lcol + 16 * g2;
            const int slot = seg * 4 + ks;
#pragma unroll
            for (int t = 0; t < 8; ++t) {
                const u16 wvl = f2bf(acc[s][t][r]);
                if (!which) WF0[(((size_t)(e*8 + t))*20 + slot)*512 + lanef*8 + elem] = wvl;
                else        WF1[(((size_t)(e*8 + t))*16 + slot)*512 + lanef*8 + elem] = wvl;
            }
        }
    }
}

__global__ void bucket_kernel(const float* __restrict__ attrs,
                              int* __restrict__ cnt, int* __restrict__ lists)
{
    __shared__ int lcnt[E_];
    __shared__ int lbase[E_];
    const int n = blockIdx.x * 256 + threadIdx.x;
    if (threadIdx.x < E_) lcnt[threadIdx.x] = 0;
    __syncthreads();
    int e = 0, my = 0;
    if (n < N_NODES) {
        const float* a = attrs + (size_t)n * E_;
#pragma unroll
        for (int i = 0; i < E_; ++i) if (a[i] > 0.5f) e = i;
        my = atomicAdd(&lcnt[e], 1);
    }
    __syncthreads();
    if (threadIdx.x < E_) lbase[threadIdx.x] = atomicAdd(&cnt[threadIdx.x], lcnt[threadIdx.x]);
    __syncthreads();
    if (n < N_NODES) lists[e*N_NODES + lbase[e] + my] = n;
}

// Main: 16 same-element nodes/block, 512 threads = 8 waves, NON-persistent.
// A-panel chunked into 3 (scalar 20 slots / vector q01 24 / vector q23 24),
// double-buffered 2x24 slots = 49,152 B LDS -> 3 blocks/CU (24 waves).
// Between barriers: build chunk c+1 (VALU+LDS-write, buf^1) co-issues with
// MFMA chunk c (L2 B-loads + LDS-read + MFMA, buf). Overlap across the 3
// resident blocks hides HBM/L2 latency statistically.
__global__ __launch_bounds__(512, 6) void main_kernel(
    const float* __restrict__ feats, const float* __restrict__ sc,
    const int* __restrict__ cnt, const int* __restrict__ lists,
    const u16* __restrict__ WF0, const u16* __restrict__ WF1,
    float* __restrict__ out)
{
    __shared__ __align__(16) u16 A2[2][24 * 512];   // 49,152 B (reused as out-stage)

    const int tid = threadIdx.x;
    const int bx = blockIdx.x;

    // uniform tile search
    int e = -1, tile = 0, accT = 0;
#pragma unroll
    for (int i = 0; i < E_; ++i) {
        const int ci = cnt[i];
        const int t = (ci + NT_ - 1) >> 4;
        if (e < 0 && bx < accT + t) { e = i; tile = bx - accT; }
        accT += t;
    }
    if (e < 0) return;
    const int nvalid = min(NT_, cnt[e] - tile * NT_);

    const int node = tid >> 5;          // 0..15
    const int ch   = tid & 31;
    const int n = (node < nvalid) ? lists[e*N_NODES + tile*NT_ + node] : -1;

    float4 f0 = make_float4(0.f,0.f,0.f,0.f), f1 = f0, f2 = f0, f3 = f0;
    if (n >= 0) {
        const float* f = feats + (size_t)n * 512;
        f0 = *(const float4*)(f + ch*4);
        f1 = *(const float4*)(f + 128 + ch*12);
        f2 = *(const float4*)(f + 128 + ch*12 + 4);
        f3 = *(const float4*)(f + 128 + ch*12 + 8);
    }
    const float Sa[4]  = {f0.x, f0.y, f0.z, f0.w};
    const float Va[12] = {f1.x,f1.y,f1.z,f1.w, f2.x,f2.y,f2.z,f2.w, f3.x,f3.y,f3.z,f3.w};

    const int lane  = node + 16 * (ch & 3);
    const int ksl   = ch >> 3;
    const int ebase = ((ch >> 2) & 1) * 4;
    const int lanep = lane ^ (ksl << 1);           // XOR swizzle (involution)
    u16* bpA = &A2[0][lanep*8 + ebase];
    u16* bpB = &A2[1][lanep*8 + ebase];

    // ---------- build chunk0 (scalar panels: S,S2,VV,S3,S*VV) -> A2[0] ----------
    {
        u16 fs[5][4];
#pragma unroll
        for (int i = 0; i < 4; ++i) {
            const float S  = Sa[i];
            const float V0 = Va[3*i], V1 = Va[3*i+1], V2 = Va[3*i+2];
            const float S2 = S * S;
            const float VV = V0*V0 + V1*V1 + V2*V2;
            fs[0][i] = f2bf(S);
            fs[1][i] = f2bf(S2);
            fs[2][i] = f2bf(VV);
            fs[3][i] = f2bf(S2 * S);
            fs[4][i] = f2bf(S * VV);
        }
#pragma unroll
        for (int p = 0; p < 5; ++p)
            *(ushort4*)&bpA[(p*4 + ksl) * 512] = *(ushort4*)fs[p];
    }
    __syncthreads();

    const int w = tid >> 6, l = tid & 63;
    const int lcol = l & 15, g = l >> 4;
    const int col = w*16 + lcol;
    const u16* WB0 = WF0 + ((size_t)(e*8 + w)) * (20*512) + l*8;
    const u16* WB1 = WF1 + ((size_t)(e*8 + w)) * (16*512) + l*8;

    f32x4 accS = {0.f, 0.f, 0.f, 0.f};
    f32x4 accV0 = accS, accV1 = accS, accV2 = accS;

    // ---------- iter0: build chunk1 (Vm, S*Vm) -> A2[1]; MFMA chunk0 ----------
    {
        u16 fs[6][4];
#pragma unroll
        for (int i = 0; i < 4; ++i) {
            const float S  = Sa[i];
            const float Vm[3] = {Va[3*i], Va[3*i+1], Va[3*i+2]};
#pragma unroll
            for (int m = 0; m < 3; ++m) {
                fs[m][i]     = f2bf(Vm[m]);        // q0
                fs[3+m][i]   = f2bf(S * Vm[m]);    // q1
            }
        }
#pragma unroll
        for (int t = 0; t < 6; ++t)
            *(ushort4*)&bpB[(t*4 + ksl) * 512] = *(ushort4*)fs[t];
    }
#pragma unroll
    for (int ks2 = 0; ks2 < 4; ++ks2) {
        short8 bS[5];
#pragma unroll
        for (int p = 0; p < 5; ++p) bS[p] = *(const short8*)(WB0 + (p*4 + ks2) * 512);
        const int lp8 = (l ^ (ks2 << 1)) * 8;
#pragma unroll
        for (int p = 0; p < 5; ++p) {
            const short8 a = *(const short8*)&A2[0][(p*4 + ks2)*512 + lp8];
            accS = __builtin_amdgcn_mfma_f32_16x16x32_bf16(a, bS[p], accS, 0, 0, 0);
        }
    }
    __syncthreads();

    // ---------- iter1: build chunk2 (S2*Vm, VV*Vm) -> A2[0]; sc prefetch; MFMA chunk1 ----------
    {
        u16 fs[6][4];
#pragma unroll
        for (int i = 0; i < 4; ++i) {
            const float S  = Sa[i];
            const float V0 = Va[3*i], V1 = Va[3*i+1], V2 = Va[3*i+2];
            const float S2 = S * S;
            const float VV = V0*V0 + V1*V1 + V2*V2;
            const float Vm[3] = {V0, V1, V2};
#pragma unroll
            for (int m = 0; m < 3; ++m) {
                fs[m][i]   = f2bf(S2 * Vm[m]);     // q2
                fs[3+m][i] = f2bf(VV * Vm[m]);     // q3
            }
        }
#pragma unroll
        for (int t = 0; t < 6; ++t)
            *(ushort4*)&bpA[(t*4 + ksl) * 512] = *(ushort4*)fs[t];
    }
    float4 scR0 = make_float4(0.f,0.f,0.f,0.f), scR1 = scR0, scR2 = scR0, scR3 = scR0;
    if (n >= 0) {
        const float* sp = sc + (size_t)n * 512 + ch * 4;
        scR0 = *(const float4*)(sp);
        scR1 = *(const float4*)(sp + 128);
        scR2 = *(const float4*)(sp + 256);
        scR3 = *(const float4*)(sp + 384);
    }
#pragma unroll
    for (int ks2 = 0; ks2 < 4; ++ks2) {
        const short8 b0 = *(const short8*)(WB1 + (0*4 + ks2) * 512);
        const short8 b1 = *(const short8*)(WB1 + (1*4 + ks2) * 512);
        const int lp8 = (l ^ (ks2 << 1)) * 8;
        {
            const short8 a0 = *(const short8*)&A2[1][(0*4 + ks2)*512 + lp8];
            accV0 = __builtin_amdgcn_mfma_f32_16x16x32_bf16(a0, b0, accV0, 0, 0, 0);
            const short8 a1 = *(const short8*)&A2[1][(1*4 + ks2)*512 + lp8];
            accV1 = __builtin_amdgcn_mfma_f32_16x16x32_bf16(a1, b0, accV1, 0, 0, 0);
            const short8 a2 = *(const short8*)&A2[1][(2*4 + ks2)*512 + lp8];
            accV2 = __builtin_amdgcn_mfma_f32_16x16x32_bf16(a2, b0, accV2, 0, 0, 0);
        }
        {
            const short8 a0 = *(const short8*)&A2[1][(3*4 + ks2)*512 + lp8];
            accV0 = __builtin_amdgcn_mfma_f32_16x16x32_bf16(a0, b1, accV0, 0, 0, 0);
            const short8 a1 = *(const short8*)&A2[1][(4*4 + ks2)*512 + lp8];
            accV1 = __builtin_amdgcn_mfma_f32_16x16x32_bf16(a1, b1, accV1, 0, 0, 0);
            const short8 a2 = *(const short8*)&A2[1][(5*4 + ks2)*512 + lp8];
            accV2 = __builtin_amdgcn_mfma_f32_16x16x32_bf16(a2, b1, accV2, 0, 0, 0);
        }
    }
    __syncthreads();

    // ---------- iter2: MFMA chunk2 from A2[0] ----------
#pragma unroll
    for (int ks2 = 0; ks2 < 4; ++ks2) {
        const short8 b2 = *(const short8*)(WB1 + (2*4 + ks2) * 512);
        const short8 b3 = *(const short8*)(WB1 + (3*4 + ks2) * 512);
        const int lp8 = (l ^ (ks2 << 1)) * 8;
        {
            const short8 a0 = *(const short8*)&A2[0][(0*4 + ks2)*512 + lp8];
            accV0 = __builtin_amdgcn_mfma_f32_16x16x32_bf16(a0, b2, accV0, 0, 0, 0);
            const short8 a1 = *(const short8*)&A2[0][(1*4 + ks2)*512 + lp8];
            accV1 = __builtin_amdgcn_mfma_f32_16x16x32_bf16(a1, b2, accV1, 0, 0, 0);
            const short8 a2 = *(const short8*)&A2[0][(2*4 + ks2)*512 + lp8];
            accV2 = __builtin_amdgcn_mfma_f32_16x16x32_bf16(a2, b2, accV2, 0, 0, 0);
        }
        {
            const short8 a0 = *(const short8*)&A2[0][(3*4 + ks2)*512 + lp8];
            accV0 = __builtin_amdgcn_mfma_f32_16x16x32_bf16(a0, b3, accV0, 0, 0, 0);
            const short8 a1 = *(const short8*)&A2[0][(4*4 + ks2)*512 + lp8];
            accV1 = __builtin_amdgcn_mfma_f32_16x16x32_bf16(a1, b3, accV1, 0, 0, 0);
            const short8 a2 = *(const short8*)&A2[0][(5*4 + ks2)*512 + lp8];
            accV2 = __builtin_amdgcn_mfma_f32_16x16x32_bf16(a2, b3, accV2, 0, 0, 0);
        }
    }
    __syncthreads();

    // ---------- epilogue: stage in LDS, coalesced stores ----------
    float* OutB = (float*)&A2[0][0];   // 16 x 516 floats = 33,024 B
#pragma unroll
    for (int r = 0; r < 4; ++r) {
        const int nd = 4*g + r;
        OutB[nd*516 + col] = accS[r];
        OutB[nd*516 + 128 + 3*col + 0] = accV0[r];
        OutB[nd*516 + 128 + 3*col + 1] = accV1[r];
        OutB[nd*516 + 128 + 3*col + 2] = accV2[r];
    }
    __syncthreads();

    if (n >= 0) {
        const size_t gb = (size_t)n * 512 + ch * 4;
        const float4 v0 = *(const float4*)&OutB[node*516 + ch*4];
        const float4 v1 = *(const float4*)&OutB[node*516 + ch*4 + 128];
        const float4 v2 = *(const float4*)&OutB[node*516 + ch*4 + 256];
        const float4 v3 = *(const float4*)&OutB[node*516 + ch*4 + 384];
        float4 o0, o1, o2, o3;
        o0.x=v0.x+scR0.x; o0.y=v0.y+scR0.y; o0.z=v0.z+scR0.z; o0.w=v0.w+scR0.w;
        o1.x=v1.x+scR1.x; o1.y=v1.y+scR1.y; o1.z=v1.z+scR1.z; o1.w=v1.w+scR1.w;
        o2.x=v2.x+scR2.x; o2.y=v2.y+scR2.y; o2.z=v2.z+scR2.z; o2.w=v2.w+scR2.w;
        o3.x=v3.x+scR3.x; o3.y=v3.y+scR3.y; o3.z=v3.z+scR3.z; o3.w=v3.w+scR3.w;
        *(float4*)(out + gb)       = o0;
        *(float4*)(out + gb + 128) = o1;
        *(float4*)(out + gb + 256) = o2;
        *(float4*)(out + gb + 384) = o3;
    }
}

extern "C" void kernel_launch(void* const* d_in, const int* in_sizes, int n_in,
                              void* d_out, int out_size, void* d_ws, size_t ws_size,
                              hipStream_t stream) {
    const float* feats = (const float*)d_in[0];
    const float* attrs = (const float*)d_in[1];
    const float* sc    = (const float*)d_in[2];
    const float* tp2   = (const float*)d_in[3];
    const float* tp3   = (const float*)d_in[4];
    const float* c00   = (const float*)d_in[5];
    const float* c01   = (const float*)d_in[6];
    const float* c10   = (const float*)d_in[7];
    const float* c11   = (const float*)d_in[8];
    const float* c20   = (const float*)d_in[9];
    const float* c21   = (const float*)d_in[10];
    const float* lin0  = (const float*)d_in[11];
    const float* lin1  = (const float*)d_in[12];
    float* out = (float*)d_out;

    char* ws = (char*)d_ws;
    u16* WF0   = (u16*)(ws);
    u16* WF1   = (u16*)(ws + WF0_BYTES);
    int* cnt   = (int*)(ws + CNT_OFF);
    int* lists = (int*)(ws + LIST_OFF);

    hipMemsetAsync(cnt, 0, 64, stream);
    hipLaunchKernelGGL(prep_weights_kernel, dim3(E_*9), dim3(256), 0, stream,
                       tp2, tp3, c00, c10, c20, c01, c11, c21, lin0, lin1, WF0, WF1);
    hipLaunchKernelGGL(bucket_kernel, dim3((N_NODES + 255)/256), dim3(256), 0, stream,
                       attrs, cnt, lists);
    hipLaunchKernelGGL(main_kernel, dim3(NBLK_MAIN), dim3(512), 0, stream,
                       feats, sc, cnt, lists, WF0, WF1, out);
}

// Round 7
// 116.642 us; speedup vs baseline: 1.2794x; 1.0058x over previous
//
#include <hip/hip_runtime.h>

typedef unsigned short u16;
typedef __attribute__((ext_vector_type(8))) short short8;
typedef __attribute__((ext_vector_type(4))) float f32x4;

#define N_NODES 50000
#define C_ 128
#define E_ 10
#define NT_ 16
#define NBLK_MAIN 3200
#define K0_ 640
#define K1_ 512

// fragment-linear weight buffers:
// WF0: [E][8 col-sections][20 slots][64 lanes][8 elems] bf16  (slot = p*4+ks)
// WF1: [E][8 col-sections][16 slots][64 lanes][8 elems] bf16  (slot = q*4+ks)
#define WF0_BYTES (E_ * 8 * 20 * 512 * 2)        // 1,638,400
#define WF1_BYTES (E_ * 8 * 16 * 512 * 2)        // 1,310,720
#define CNT_OFF   (WF0_BYTES + WF1_BYTES)
#define LIST_OFF  (CNT_OFF + 64)

__device__ __forceinline__ u16 f2bf(float f){ union{unsigned u; float f;} v; v.f = f; unsigned u = v.u; u += 0x7FFFu + ((u>>16)&1u); return (u16)(u>>16); }
__device__ __forceinline__ unsigned cvtpk(float a, float b){
    unsigned r;
    asm("v_cvt_pk_bf16_f32 %0, %1, %2" : "=v"(r) : "v"(a), "v"(b));
    return r;
}

// MFMA-based weight prep (validated r4-r6): grid = E_*9 blocks of 256 threads.
__global__ __launch_bounds__(256) void prep_weights_kernel(
    const float* __restrict__ tp2, const float* __restrict__ tp3,
    const float* __restrict__ c00, const float* __restrict__ c10, const float* __restrict__ c20,
    const float* __restrict__ c01, const float* __restrict__ c11, const float* __restrict__ c21,
    const float* __restrict__ lin0, const float* __restrict__ lin1,
    u16* __restrict__ WF0, u16* __restrict__ WF1)
{
    const int b = blockIdx.x;
    const int e = b / 9, kb = b % 9;
    const int which = (kb >= 5) ? 1 : 0;
    const int seg = which ? kb - 5 : kb;
    const float* __restrict__ lin = which ? lin1 : lin0;

    __shared__ u16 R[128 * 136];
    __shared__ u16 LT[128 * 132];

    const int tid = threadIdx.x;
    const float NC = 0.08838834764831845f;

    for (int t = tid; t < 128 * 32; t += 256) {
        const int jj = t >> 5, c4 = (t & 31) << 2;
        const float4 v = *(const float4*)(lin + jj * 128 + c4);
        LT[(c4 + 0) * 132 + jj] = f2bf(v.x * NC);
        LT[(c4 + 1) * 132 + jj] = f2bf(v.y * NC);
        LT[(c4 + 2) * 132 + jj] = f2bf(v.z * NC);
        LT[(c4 + 3) * 132 + jj] = f2bf(v.w * NC);
    }

    {
        const int c = tid >> 1, jh = (tid & 1) * 64;
        const float i128 = 0.08838834764831845f;
        const float i256 = 0.0625f;
        const float i512 = 0.04419417382415922f;
        const float I3   = 0.5773502691896258f;
        const float I9   = I3 * I3;
        const float t2_0 = tp2[0*C_+c], t2_1 = tp2[1*C_+c], t2_2 = tp2[2*C_+c], t2_3 = tp2[3*C_+c];
        const float t3_0 = tp3[0*C_+c], t3_1 = tp3[1*C_+c], t3_2 = tp3[2*C_+c];
        const float t3_3 = tp3[3*C_+c], t3_4 = tp3[4*C_+c], t3_5 = tp3[5*C_+c];
        const float t3_6 = tp3[6*C_+c], t3_7 = tp3[7*C_+c];

        const float* P0; const float* P1 = nullptr; const float* P2 = nullptr;
        float a0 = 0.f, a1 = 0.f, a2 = 0.f;
        if (!which) {
            const float* C0 = c00 + (size_t)e * C_   * C_;
            const float* C1 = c10 + (size_t)e * 2*C_ * C_;
            const float* C2 = c20 + (size_t)e * 4*C_ * C_;
            switch (seg) {
            case 0: P0 = C0 + c*C_;          a0 = i128; break;
            case 1: P0 = C1 + c*C_;          a0 = t2_0 * i256; break;
            case 2: P0 = C1 + (C_+c)*C_;     a0 = t2_3 * I3 * i256; break;
            case 3: P0 = C2 + c*C_;          a0 = t3_0 * t2_0 * i512; break;
            default:
                P0 = C2 + (C_+c)*C_;         a0 = t3_3 * t2_1 * I9 * i512;
                P1 = C2 + (2*C_+c)*C_;       a1 = t3_5 * t2_2 * I9 * i512;
                P2 = C2 + (3*C_+c)*C_;       a2 = t3_6 * t2_3 * I3 * i512; break;
            }
        } else {
            const float* C0 = c01 + (size_t)e * C_   * C_;
            const float* C1 = c11 + (size_t)e * 2*C_ * C_;
            const float* C2 = c21 + (size_t)e * 4*C_ * C_;
            switch (seg) {
            case 0: P0 = C0 + c*C_;          a0 = i128; break;
            case 1: P0 = C1 + c*C_;          a0 = t2_1 * I3 * i256;
                    P1 = C1 + (C_+c)*C_;     a1 = t2_2 * I3 * i256; break;
            case 2: P0 = C2 + c*C_;          a0 = t3_1 * t2_0 * I3 * i512;
                    P1 = C2 + (C_+c)*C_;     a1 = t3_2 * t2_1 * I9 * i512;
                    P2 = C2 + (2*C_+c)*C_;   a2 = t3_4 * t2_2 * I9 * i512; break;
            default: P0 = C2 + (3*C_+c)*C_;  a0 = t3_7 * t2_3 * I9 * i512; break;
            }
        }
        for (int j4 = 0; j4 < 64; j4 += 4) {
            const int jj = jh + j4;
            const float4 v = *(const float4*)(P0 + jj);
            float r0 = a0*v.x, r1 = a0*v.y, r2 = a0*v.z, r3 = a0*v.w;
            if (P1) {
                const float4 u = *(const float4*)(P1 + jj);
                r0 += a1*u.x; r1 += a1*u.y; r2 += a1*u.z; r3 += a1*u.w;
            }
            if (P2) {
                const float4 u = *(const float4*)(P2 + jj);
                r0 += a2*u.x; r1 += a2*u.y; r2 += a2*u.z; r3 += a2*u.w;
            }
            ushort4 st; st.x = f2bf(r0); st.y = f2bf(r1); st.z = f2bf(r2); st.w = f2bf(r3);
            *(ushort4*)&R[c * 136 + jj] = st;
        }
    }
    __syncthreads();

    const int wv = tid >> 6, l = tid & 63;
    const int lcol = l & 15, gD = l >> 4;
    f32x4 acc[2][8];
#pragma unroll
    for (int s = 0; s < 2; ++s)
#pragma unroll
        for (int t = 0; t < 8; ++t) acc[s][t] = (f32x4){0.f, 0.f, 0.f, 0.f};

#pragma unroll
    for (int ks2 = 0; ks2 < 4; ++ks2) {
        const int jj0 = ks2 * 32 + gD * 4;
        short8 bf[8];
#pragma unroll
        for (int t = 0; t < 8; ++t) {
            const int colB = t * 16 + lcol;
            union { unsigned long long q[2]; short8 v; } u;
            u.q[0] = *(const unsigned long long*)&LT[colB * 132 + jj0];
            u.q[1] = *(const unsigned long long*)&LT[colB * 132 + jj0 + 16];
            bf[t] = u.v;
        }
#pragma unroll
        for (int s = 0; s < 2; ++s) {
            const int krow = (wv + s * 4) * 16 + lcol;
            union { unsigned long long q[2]; short8 v; } ua;
            ua.q[0] = *(const unsigned long long*)&R[krow * 136 + jj0];
            ua.q[1] = *(const unsigned long long*)&R[krow * 136 + jj0 + 16];
#pragma unroll
            for (int t = 0; t < 8; ++t)
                acc[s][t] = __builtin_amdgcn_mfma_f32_16x16x32_bf16(ua.v, bf[t], acc[s][t], 0, 0, 0);
        }
    }

#pragma unroll
    for (int s = 0; s < 2; ++s) {
#pragma unroll
        for (int r = 0; r < 4; ++r) {
            const int k = (wv + s * 4) * 16 + 4 * gD + r;
            const int ks = k >> 5, r2 = k & 31;
            const int eh = r2 >> 4, g2 = (r2 >> 2) & 3, el = r2 & 3;
            const int elem = eh * 4 + el;
            const int lanef = lcol + 16 * g2;
            const int slot = seg * 4 + ks;
#pragma unroll
            for (int t = 0; t < 8; ++t) {
                const u16 wvl = f2bf(acc[s][t][r]);
                if (!which) WF0[(((size_t)(e*8 + t))*20 + slot)*512 + lanef*8 + elem] = wvl;
                else        WF1[(((size_t)(e*8 + t))*16 + slot)*512 + lanef*8 + elem] = wvl;
            }
        }
    }
}

__global__ void bucket_kernel(const float* __restrict__ attrs,
                              int* __restrict__ cnt, int* __restrict__ lists)
{
    __shared__ int lcnt[E_];
    __shared__ int lbase[E_];
    const int n = blockIdx.x * 256 + threadIdx.x;
    if (threadIdx.x < E_) lcnt[threadIdx.x] = 0;
    __syncthreads();
    int e = 0, my = 0;
    if (n < N_NODES) {
        const float* a = attrs + (size_t)n * E_;
#pragma unroll
        for (int i = 0; i < E_; ++i) if (a[i] > 0.5f) e = i;
        my = atomicAdd(&lcnt[e], 1);
    }
    __syncthreads();
    if (threadIdx.x < E_) lbase[threadIdx.x] = atomicAdd(&cnt[threadIdx.x], lcnt[threadIdx.x]);
    __syncthreads();
    if (n < N_NODES) lists[e*N_NODES + lbase[e] + my] = n;
}

// Main: 16 same-element nodes/block, 256 threads = 4 waves, each wave owns
// 32 output cols (2 B-frags / 2 MFMAs per A-fragment read -> A-LDS traffic
// halved vs 8x16-col waves). 3-chunk double-buffered A panel (48 KB).
// Build: thread = (node, cg) handles 8 channels c = cg*8+i; per-thread
// frag coords: ks=cg>>2, eh=(cg>>1)&1, gbase=(cg&1)*2 (all compile-time
// uniform per thread). bf16 pack via v_cvt_pk_bf16_f32.
__global__ __launch_bounds__(256, 3) void main_kernel(
    const float* __restrict__ feats, const float* __restrict__ sc,
    const int* __restrict__ cnt, const int* __restrict__ lists,
    const u16* __restrict__ WF0, const u16* __restrict__ WF1,
    float* __restrict__ out)
{
    __shared__ __align__(16) u16 A2[2][24 * 512];   // 49,152 B (reused as out-stage)

    const int tid = threadIdx.x;
    const int bx = blockIdx.x;

    // uniform tile search
    int e = -1, tile = 0, accT = 0;
#pragma unroll
    for (int i = 0; i < E_; ++i) {
        const int ci = cnt[i];
        const int t = (ci + NT_ - 1) >> 4;
        if (e < 0 && bx < accT + t) { e = i; tile = bx - accT; }
        accT += t;
    }
    if (e < 0) return;
    const int nvalid = min(NT_, cnt[e] - tile * NT_);

    const int node = tid >> 4;          // 0..15
    const int cg   = tid & 15;          // 8 channels: c = cg*8 + i
    const int n = (node < nvalid) ? lists[e*N_NODES + tile*NT_ + node] : -1;

    // ---------- load feats (8 float4) ----------
    float4 s0 = make_float4(0.f,0.f,0.f,0.f), s1 = s0;
    float4 v4[6];
#pragma unroll
    for (int k = 0; k < 6; ++k) v4[k] = s0;
    if (n >= 0) {
        const float* f = feats + (size_t)n * 512;
        s0 = *(const float4*)(f + cg*8);
        s1 = *(const float4*)(f + cg*8 + 4);
#pragma unroll
        for (int k = 0; k < 6; ++k) v4[k] = *(const float4*)(f + 128 + cg*24 + 4*k);
    }
    float S[8]  = {s0.x,s0.y,s0.z,s0.w, s1.x,s1.y,s1.z,s1.w};
    float V[24] = {v4[0].x,v4[0].y,v4[0].z,v4[0].w, v4[1].x,v4[1].y,v4[1].z,v4[1].w,
                   v4[2].x,v4[2].y,v4[2].z,v4[2].w, v4[3].x,v4[3].y,v4[3].z,v4[3].w,
                   v4[4].x,v4[4].y,v4[4].z,v4[4].w, v4[5].x,v4[5].y,v4[5].z,v4[5].w};
    float S2[8], VV[8];
#pragma unroll
    for (int i = 0; i < 8; ++i) {
        S2[i] = S[i]*S[i];
        VV[i] = V[3*i]*V[3*i] + V[3*i+1]*V[3*i+1] + V[3*i+2]*V[3*i+2];
    }

    // per-thread fragment coordinates
    const int ksl   = cg >> 2;
    const int eh    = (cg >> 1) & 1;
    const int gb    = (cg & 1) * 2;
    const int lp0   = (node + 16*gb)        ^ (ksl << 1);
    const int lp1   = (node + 16*(gb + 1))  ^ (ksl << 1);
    const int off0  = lp0*8 + 4*eh;
    const int off1  = lp1*8 + 4*eh;

    // write one slot's 8 values (i=0..3 -> lane lp0, i=4..7 -> lane lp1)
#define WSLOT(BUF, SLOT, V0,V1,V2,V3,V4,V5,V6,V7) do { \
        uint2 w0_, w1_; \
        w0_.x = cvtpk((V0),(V1)); w0_.y = cvtpk((V2),(V3)); \
        w1_.x = cvtpk((V4),(V5)); w1_.y = cvtpk((V6),(V7)); \
        *(uint2*)&A2[BUF][(SLOT)*512 + off0] = w0_; \
        *(uint2*)&A2[BUF][(SLOT)*512 + off1] = w1_; \
    } while (0)

    // ---------- build chunk0: scalar panels {S,S2,VV,S3,S*VV} -> A2[0] ----------
    WSLOT(0, 0*4 + ksl, S[0],S[1],S[2],S[3],S[4],S[5],S[6],S[7]);
    WSLOT(0, 1*4 + ksl, S2[0],S2[1],S2[2],S2[3],S2[4],S2[5],S2[6],S2[7]);
    WSLOT(0, 2*4 + ksl, VV[0],VV[1],VV[2],VV[3],VV[4],VV[5],VV[6],VV[7]);
    WSLOT(0, 3*4 + ksl, S2[0]*S[0],S2[1]*S[1],S2[2]*S[2],S2[3]*S[3],
                        S2[4]*S[4],S2[5]*S[5],S2[6]*S[6],S2[7]*S[7]);
    WSLOT(0, 4*4 + ksl, S[0]*VV[0],S[1]*VV[1],S[2]*VV[2],S[3]*VV[3],
                        S[4]*VV[4],S[5]*VV[5],S[6]*VV[6],S[7]*VV[7]);
    __syncthreads();

    // MFMA-side coordinates
    const int w4 = tid >> 6, l = tid & 63;
    const int lcol = l & 15, g = l >> 4;
    const int col0 = (2*w4)*16 + lcol;
    const int col1 = col0 + 16;
    const u16* WB0a = WF0 + ((size_t)(e*8 + 2*w4))     * (20*512) + l*8;
    const u16* WB0b = WB0a + 20*512;
    const u16* WB1a = WF1 + ((size_t)(e*8 + 2*w4))     * (16*512) + l*8;
    const u16* WB1b = WB1a + 16*512;

    f32x4 accS0 = {0.f,0.f,0.f,0.f}, accS1 = accS0;
    f32x4 accV[3][2];
#pragma unroll
    for (int m = 0; m < 3; ++m) { accV[m][0] = accS0; accV[m][1] = accS0; }

    // ---------- region1: build chunk1 {Vm, S*Vm} -> A2[1]  |  MFMA chunk0 ----------
#pragma unroll
    for (int m = 0; m < 3; ++m) {
        WSLOT(1, m*4 + ksl,     V[0*3+m],V[1*3+m],V[2*3+m],V[3*3+m],
                                V[4*3+m],V[5*3+m],V[6*3+m],V[7*3+m]);
        WSLOT(1, (3+m)*4 + ksl, S[0]*V[0*3+m],S[1]*V[1*3+m],S[2]*V[2*3+m],S[3]*V[3*3+m],
                                S[4]*V[4*3+m],S[5]*V[5*3+m],S[6]*V[6*3+m],S[7]*V[7*3+m]);
    }
#pragma unroll
    for (int ks2 = 0; ks2 < 4; ++ks2) {
        const int lp8 = (l ^ (ks2 << 1)) * 8;
#pragma unroll
        for (int p = 0; p < 5; ++p) {
            const short8 a  = *(const short8*)&A2[0][(p*4 + ks2)*512 + lp8];
            const short8 b0 = *(const short8*)(WB0a + (p*4 + ks2)*512);
            const short8 b1 = *(const short8*)(WB0b + (p*4 + ks2)*512);
            accS0 = __builtin_amdgcn_mfma_f32_16x16x32_bf16(a, b0, accS0, 0, 0, 0);
            accS1 = __builtin_amdgcn_mfma_f32_16x16x32_bf16(a, b1, accS1, 0, 0, 0);
        }
    }
    __syncthreads();

    // ---------- region2: build chunk2 {S2*Vm, VV*Vm} -> A2[0] | sc prefetch | MFMA chunk1 ----------
#pragma unroll
    for (int m = 0; m < 3; ++m) {
        WSLOT(0, m*4 + ksl,     S2[0]*V[0*3+m],S2[1]*V[1*3+m],S2[2]*V[2*3+m],S2[3]*V[3*3+m],
                                S2[4]*V[4*3+m],S2[5]*V[5*3+m],S2[6]*V[6*3+m],S2[7]*V[7*3+m]);
        WSLOT(0, (3+m)*4 + ksl, VV[0]*V[0*3+m],VV[1]*V[1*3+m],VV[2]*V[2*3+m],VV[3]*V[3*3+m],
                                VV[4]*V[4*3+m],VV[5]*V[5*3+m],VV[6]*V[6*3+m],VV[7]*V[7*3+m]);
    }
    float4 scR[8];
#pragma unroll
    for (int j = 0; j < 8; ++j) scR[j] = make_float4(0.f,0.f,0.f,0.f);
    if (n >= 0) {
        const float* sp = sc + (size_t)n * 512 + cg * 4;
#pragma unroll
        for (int j = 0; j < 8; ++j) scR[j] = *(const float4*)(sp + 64*j);
    }
#pragma unroll
    for (int ks2 = 0; ks2 < 4; ++ks2) {
        const int lp8 = (l ^ (ks2 << 1)) * 8;
#pragma unroll
        for (int q = 0; q < 2; ++q) {
            const short8 b0 = *(const short8*)(WB1a + (q*4 + ks2)*512);
            const short8 b1 = *(const short8*)(WB1b + (q*4 + ks2)*512);
#pragma unroll
            for (int m = 0; m < 3; ++m) {
                const short8 a = *(const short8*)&A2[1][((q*3 + m)*4 + ks2)*512 + lp8];
                accV[m][0] = __builtin_amdgcn_mfma_f32_16x16x32_bf16(a, b0, accV[m][0], 0, 0, 0);
                accV[m][1] = __builtin_amdgcn_mfma_f32_16x16x32_bf16(a, b1, accV[m][1], 0, 0, 0);
            }
        }
    }
    __syncthreads();

    // ---------- region3: MFMA chunk2 from A2[0] ----------
#pragma unroll
    for (int ks2 = 0; ks2 < 4; ++ks2) {
        const int lp8 = (l ^ (ks2 << 1)) * 8;
#pragma unroll
        for (int q = 0; q < 2; ++q) {
            const short8 b0 = *(const short8*)(WB1a + ((2+q)*4 + ks2)*512);
            const short8 b1 = *(const short8*)(WB1b + ((2+q)*4 + ks2)*512);
#pragma unroll
            for (int m = 0; m < 3; ++m) {
                const short8 a = *(const short8*)&A2[0][((q*3 + m)*4 + ks2)*512 + lp8];
                accV[m][0] = __builtin_amdgcn_mfma_f32_16x16x32_bf16(a, b0, accV[m][0], 0, 0, 0);
                accV[m][1] = __builtin_amdgcn_mfma_f32_16x16x32_bf16(a, b1, accV[m][1], 0, 0, 0);
            }
        }
    }
    __syncthreads();

    // ---------- epilogue: stage in LDS, coalesced stores ----------
    float* OutB = (float*)&A2[0][0];   // 16 x 516 floats = 33,024 B
#pragma unroll
    for (int r = 0; r < 4; ++r) {
        const int nd = 4*g + r;
        OutB[nd*516 + col0] = accS0[r];
        OutB[nd*516 + col1] = accS1[r];
#pragma unroll
        for (int m = 0; m < 3; ++m) {
            OutB[nd*516 + 128 + 3*col0 + m] = accV[m][0][r];
            OutB[nd*516 + 128 + 3*col1 + m] = accV[m][1][r];
        }
    }
    __syncthreads();

    if (n >= 0) {
        const size_t gb2 = (size_t)n * 512 + cg * 4;
#pragma unroll
        for (int j = 0; j < 8; ++j) {
            const float4 vres = *(const float4*)&OutB[node*516 + cg*4 + 64*j];
            float4 o;
            o.x = vres.x + scR[j].x; o.y = vres.y + scR[j].y;
            o.z = vres.z + scR[j].z; o.w = vres.w + scR[j].w;
            *(float4*)(out + gb2 + 64*j) = o;
        }
    }
#undef WSLOT
}

extern "C" void kernel_launch(void* const* d_in, const int* in_sizes, int n_in,
                              void* d_out, int out_size, void* d_ws, size_t ws_size,
                              hipStream_t stream) {
    const float* feats = (const float*)d_in[0];
    const float* attrs = (const float*)d_in[1];
    const float* sc    = (const float*)d_in[2];
    const float* tp2   = (const float*)d_in[3];
    const float* tp3   = (const float*)d_in[4];
    const float* c00   = (const float*)d_in[5];
    const float* c01   = (const float*)d_in[6];
    const float* c10   = (const float*)d_in[7];
    const float* c11   = (const float*)d_in[8];
    const float* c20   = (const float*)d_in[9];
    const float* c21   = (const float*)d_in[10];
    const float* lin0  = (const float*)d_in[11];
    const float* lin1  = (const float*)d_in[12];
    float* out = (float*)d_out;

    char* ws = (char*)d_ws;
    u16* WF0   = (u16*)(ws);
    u16* WF1   = (u16*)(ws + WF0_BYTES);
    int* cnt   = (int*)(ws + CNT_OFF);
    int* lists = (int*)(ws + LIST_OFF);

    hipMemsetAsync(cnt, 0, 64, stream);
    hipLaunchKernelGGL(prep_weights_kernel, dim3(E_*9), dim3(256), 0, stream,
                       tp2, tp3, c00, c10, c20, c01, c11, c21, lin0, lin1, WF0, WF1);
    hipLaunchKernelGGL(bucket_kernel, dim3((N_NODES + 255)/256), dim3(256), 0, stream,
                       attrs, cnt, lists);
    hipLaunchKernelGGL(main_kernel, dim3(NBLK_MAIN), dim3(256), 0, stream,
                       feats, sc, cnt, lists, WF0, WF1, out);
}